// Round 1
// baseline (261.804 us; speedup 1.0000x reference)
//
#include <hip/hip_runtime.h>

#define DIM 256
#define NQ 8
#define NLAYERS 3
#define NPAIRS 4

// ---------------------------------------------------------------------------
// Kernel 1: build U (256x256 complex) by simulating each basis column through
// the fixed parametrized circuit. One block per column, 256 threads = 1 amp
// per thread, LDS ping-pong buffers. Wire w has bit weight 1<<(7-w) (wire 0
// is the MSB of the flat index, per the reference's reshape(B, L, 2, R)).
// ---------------------------------------------------------------------------
__global__ __launch_bounds__(256) void build_U(const float* __restrict__ params,
                                               float* __restrict__ Ure,
                                               float* __restrict__ Uim) {
  __shared__ float re[2][DIM], im[2][DIM];
  const int t = threadIdx.x;
  const int col = blockIdx.x;
  int cur = 0;
  re[0][t] = (t == col) ? 1.0f : 0.0f;
  im[0][t] = 0.0f;
  __syncthreads();
  int idx = 0;
  for (int layer = 0; layer < NLAYERS; ++layer) {
    for (int p = 0; p < NPAIRS; ++p) {
      const int i = 2 * p, j = 2 * p + 1;
      const int mi = 1 << (7 - i), mj = 1 << (7 - j);
      const float p0 = params[idx + 0], p1 = params[idx + 1];
      const float p2 = params[idx + 2], p3 = params[idx + 3];
      idx += 4;
      { // RZ(p0) on wire i: diag(e^{-i p0/2}, e^{+i p0/2}), in place
        const float ang = (t & mi) ? 0.5f * p0 : -0.5f * p0;
        const float cr = cosf(ang), sr = sinf(ang);
        const float r = re[cur][t], q = im[cur][t];
        re[cur][t] = r * cr - q * sr;
        im[cur][t] = r * sr + q * cr;
      }
      __syncthreads();
      { // RX(p1) on wire j: [[c, -i s],[-i s, c]]
        const float c = cosf(0.5f * p1), s = sinf(0.5f * p1);
        const int pt = t ^ mj;
        const float rd = re[cur][t], qd = im[cur][t];
        const float rp = re[cur][pt], qp = im[cur][pt];
        re[1 - cur][t] = c * rd + s * qp;
        im[1 - cur][t] = c * qd - s * rp;
      }
      cur = 1 - cur;
      __syncthreads();
      { // CNOT(i -> j): flip target bit where control bit set
        const int src = (t & mi) ? (t ^ mj) : t;
        re[1 - cur][t] = re[cur][src];
        im[1 - cur][t] = im[cur][src];
      }
      cur = 1 - cur;
      __syncthreads();
      { // RZ(p2) on wire j, in place
        const float ang = (t & mj) ? 0.5f * p2 : -0.5f * p2;
        const float cr = cosf(ang), sr = sinf(ang);
        const float r = re[cur][t], q = im[cur][t];
        re[cur][t] = r * cr - q * sr;
        im[cur][t] = r * sr + q * cr;
      }
      __syncthreads();
      { // RX(p3) on wire j
        const float c = cosf(0.5f * p3), s = sinf(0.5f * p3);
        const int pt = t ^ mj;
        const float rd = re[cur][t], qd = im[cur][t];
        const float rp = re[cur][pt], qp = im[cur][pt];
        re[1 - cur][t] = c * rd + s * qp;
        im[1 - cur][t] = c * qd - s * rp;
      }
      cur = 1 - cur;
      __syncthreads();
    }
  }
  // U[m][l], row-major by m
  Ure[t * DIM + col] = re[cur][t];
  Uim[t * DIM + col] = im[cur][t];
}

// ---------------------------------------------------------------------------
// Kernel 2: A = Re(U^H D U), D = diag(+1 for m<128, -1 else)  (Z on wire 0 =
// MSB). A is real symmetric. Block k computes row k; thread l computes A[k][l].
// U[m][k] reads are block-uniform (scalar), U[m][l] coalesced.
// ---------------------------------------------------------------------------
__global__ __launch_bounds__(256) void build_A(const float* __restrict__ Ure,
                                               const float* __restrict__ Uim,
                                               float* __restrict__ A) {
  const int k = blockIdx.x;
  const int l = threadIdx.x;
  float acc = 0.0f;
  for (int m = 0; m < DIM; ++m) {
    const float sgn = (m < 128) ? 1.0f : -1.0f;
    const float ukr = sgn * Ure[m * DIM + k];
    const float uki = sgn * Uim[m * DIM + k];
    acc = fmaf(ukr, Ure[m * DIM + l], acc);
    acc = fmaf(uki, Uim[m * DIM + l], acc);
  }
  A[k * DIM + l] = acc;
}

// ---------------------------------------------------------------------------
// Kernel 3: per batch element b: psi = g (wires 0-3) ⊗ h (wires 4-7),
// z = psi^T A psi, out = sigmoid(z).
// Block = 256 threads = 4 waves; each block covers 64 batch elements; wave w
// accumulates k in [64w, 64w+64) (2 tiles of 32 accumulators), partial z's
// reduced through LDS. A-row loads are wave-uniform -> scalar loads from L2.
// g is kept in LDS (dynamically indexed by the lh loop); h stays in VGPRs
// (only constant-unrolled indices) to avoid scratch spills.
// ---------------------------------------------------------------------------
__global__ __launch_bounds__(256) void qcnn_main(const float* __restrict__ x,
                                                 const float* __restrict__ A,
                                                 float* __restrict__ out) {
  __shared__ float gs[16][256];
  __shared__ float part[4][64];
  const int tid = threadIdx.x;
  const int lane = tid & 63;
  const int waveid = __builtin_amdgcn_readfirstlane(tid >> 6);
  const int elem = blockIdx.x * 64 + lane;

  const float4* xv = (const float4*)(x + (size_t)elem * 8);
  const float4 a0 = xv[0];
  const float4 a1 = xv[1];
  const float xs[8] = {a0.x, a0.y, a0.z, a0.w, a1.x, a1.y, a1.z, a1.w};
  float c[8], s[8];
#pragma unroll
  for (int w = 0; w < 8; ++w) {
    c[w] = cosf(0.5f * xs[w]);
    s[w] = sinf(0.5f * xs[w]);
  }
  // g over wires 0..3 (bit 3 of the 4-bit index = wire 0), h over wires 4..7.
  float h[16];
#pragma unroll
  for (int u = 0; u < 16; ++u) {
    const float gv = ((u & 8) ? s[0] : c[0]) * ((u & 4) ? s[1] : c[1]) *
                     ((u & 2) ? s[2] : c[2]) * ((u & 1) ? s[3] : c[3]);
    gs[u][tid] = gv;  // own column only; same-thread LDS RAW is ordered
    h[u] = ((u & 8) ? s[4] : c[4]) * ((u & 4) ? s[5] : c[5]) *
           ((u & 2) ? s[6] : c[6]) * ((u & 1) ? s[7] : c[7]);
  }

  float zpart = 0.0f;
#pragma unroll
  for (int tile = 0; tile < 2; ++tile) {
    const int k0 = waveid * 64 + tile * 32;  // wave-uniform (SGPR)
    float y[32];
#pragma unroll
    for (int t2 = 0; t2 < 32; ++t2) y[t2] = 0.0f;
#pragma unroll 1
    for (int lh = 0; lh < 16; ++lh) {
      const float gl = gs[lh][tid];
      const float* __restrict__ Abase = A + (lh * 16) * DIM + k0;
#pragma unroll
      for (int ll = 0; ll < 16; ++ll) {
        const float psi = gl * h[ll];  // psi_l = g[l>>4] * h[l&15]
        const float* __restrict__ Arow = Abase + ll * DIM;
#pragma unroll
        for (int t2 = 0; t2 < 32; ++t2) {
          // A symmetric: A[l][k0+t2] == A[k0+t2][l]
          y[t2] = fmaf(Arow[t2], psi, y[t2]);
        }
      }
    }
    // zpart += sum_k psi_k * y_k over this tile; k&15 == t2&15, kh uniform.
    float sumA = 0.0f, sumB = 0.0f;
#pragma unroll
    for (int t2 = 0; t2 < 16; ++t2) sumA = fmaf(y[t2], h[t2], sumA);
#pragma unroll
    for (int t2 = 16; t2 < 32; ++t2) sumB = fmaf(y[t2], h[t2 - 16], sumB);
    const float gA = gs[(k0 >> 4) + 0][tid];
    const float gB = gs[(k0 >> 4) + 1][tid];
    zpart = fmaf(gA, sumA, zpart);
    zpart = fmaf(gB, sumB, zpart);
  }

  part[waveid][lane] = zpart;
  __syncthreads();
  if (tid < 64) {
    const float z = part[0][lane] + part[1][lane] + part[2][lane] + part[3][lane];
    out[elem] = 1.0f / (1.0f + expf(-z));
  }
}

// ---------------------------------------------------------------------------
// ws layout (floats): Ure[65536] | Uim[65536] | A[65536]  = 768 KB total.
// Everything is recomputed every call (ws is re-poisoned between launches).
// ---------------------------------------------------------------------------
extern "C" void kernel_launch(void* const* d_in, const int* in_sizes, int n_in,
                              void* d_out, int out_size, void* d_ws, size_t ws_size,
                              hipStream_t stream) {
  const float* x = (const float*)d_in[0];
  const float* params = (const float*)d_in[1];
  float* out = (float*)d_out;
  float* Ure = (float*)d_ws;
  float* Uim = Ure + DIM * DIM;
  float* A = Uim + DIM * DIM;

  build_U<<<DIM, DIM, 0, stream>>>(params, Ure, Uim);
  build_A<<<DIM, DIM, 0, stream>>>(Ure, Uim, A);

  const int B = in_sizes[0] / NQ;  // 131072
  qcnn_main<<<B / 64, 256, 0, stream>>>(x, A, out);
}

// Round 2
// 122.962 us; speedup vs baseline: 2.1292x; 2.1292x over previous
//
#include <hip/hip_runtime.h>
#include <stdint.h>

#define DIM 256
#define NQ 8
#define NLAYERS 3
#define NPAIRS 4

typedef short bf16x8 __attribute__((ext_vector_type(8)));
typedef float f32x4 __attribute__((ext_vector_type(4)));

__device__ __forceinline__ unsigned short f2bf(float f) {
  uint32_t x = __builtin_bit_cast(uint32_t, f);
  uint32_t r = (x + 0x7FFFu + ((x >> 16) & 1u)) >> 16;  // RNE
  return (unsigned short)r;
}

// ---------------------------------------------------------------------------
// Kernel 1: build U (256x256 complex fp32) by simulating each basis column
// through the fixed parametrized circuit. One block per column, 256 threads,
// LDS ping-pong. Wire w has bit weight 1<<(7-w). (Verified correct round 1.)
// ---------------------------------------------------------------------------
__global__ __launch_bounds__(256) void build_U(const float* __restrict__ params,
                                               float* __restrict__ Ure,
                                               float* __restrict__ Uim) {
  __shared__ float re[2][DIM], im[2][DIM];
  const int t = threadIdx.x;
  const int col = blockIdx.x;
  int cur = 0;
  re[0][t] = (t == col) ? 1.0f : 0.0f;
  im[0][t] = 0.0f;
  __syncthreads();
  int idx = 0;
  for (int layer = 0; layer < NLAYERS; ++layer) {
    for (int p = 0; p < NPAIRS; ++p) {
      const int i = 2 * p, j = 2 * p + 1;
      const int mi = 1 << (7 - i), mj = 1 << (7 - j);
      const float p0 = params[idx + 0], p1 = params[idx + 1];
      const float p2 = params[idx + 2], p3 = params[idx + 3];
      idx += 4;
      { // RZ(p0) on wire i
        const float ang = (t & mi) ? 0.5f * p0 : -0.5f * p0;
        const float cr = cosf(ang), sr = sinf(ang);
        const float r = re[cur][t], q = im[cur][t];
        re[cur][t] = r * cr - q * sr;
        im[cur][t] = r * sr + q * cr;
      }
      __syncthreads();
      { // RX(p1) on wire j
        const float c = cosf(0.5f * p1), s = sinf(0.5f * p1);
        const int pt = t ^ mj;
        const float rd = re[cur][t], qd = im[cur][t];
        const float rp = re[cur][pt], qp = im[cur][pt];
        re[1 - cur][t] = c * rd + s * qp;
        im[1 - cur][t] = c * qd - s * rp;
      }
      cur = 1 - cur;
      __syncthreads();
      { // CNOT(i -> j)
        const int src = (t & mi) ? (t ^ mj) : t;
        re[1 - cur][t] = re[cur][src];
        im[1 - cur][t] = im[cur][src];
      }
      cur = 1 - cur;
      __syncthreads();
      { // RZ(p2) on wire j
        const float ang = (t & mj) ? 0.5f * p2 : -0.5f * p2;
        const float cr = cosf(ang), sr = sinf(ang);
        const float r = re[cur][t], q = im[cur][t];
        re[cur][t] = r * cr - q * sr;
        im[cur][t] = r * sr + q * cr;
      }
      __syncthreads();
      { // RX(p3) on wire j
        const float c = cosf(0.5f * p3), s = sinf(0.5f * p3);
        const int pt = t ^ mj;
        const float rd = re[cur][t], qd = im[cur][t];
        const float rp = re[cur][pt], qp = im[cur][pt];
        re[1 - cur][t] = c * rd + s * qp;
        im[1 - cur][t] = c * qd - s * rp;
      }
      cur = 1 - cur;
      __syncthreads();
    }
  }
  Ure[t * DIM + col] = re[cur][t];
  Uim[t * DIM + col] = im[cur][t];
}

// ---------------------------------------------------------------------------
// Kernel 2: A[n][k] = Re(U^H D U)[n][k] (real symmetric), written as bf16 in
// MFMA A-operand FRAGMENT ORDER so the main kernel can stage with contiguous
// global_load_lds and read with contiguous ds_read_b128:
//   elem(n,k) -> ((((n>>4)*8 + (k>>5))*4 + ((k>>3)&3))*16 + (n&15))*8 + (k&7)
// i.e. layout [n-tile(16)][k0(8)][q(4)][c(16)][j(8)], lane l=q*16+c holds
// A[nt*16+c][32*t + q*8 + j] as 8 consecutive bf16 (16 B).
// ---------------------------------------------------------------------------
__global__ __launch_bounds__(256) void build_A(const float* __restrict__ Ure,
                                               const float* __restrict__ Uim,
                                               short* __restrict__ Af) {
  const int n = blockIdx.x;
  const int kk = threadIdx.x;
  float acc = 0.0f;
  for (int m = 0; m < DIM; ++m) {
    const float sgn = (m < 128) ? 1.0f : -1.0f;
    const float ukr = sgn * Ure[m * DIM + n];
    const float uki = sgn * Uim[m * DIM + n];
    acc = fmaf(ukr, Ure[m * DIM + kk], acc);
    acc = fmaf(uki, Uim[m * DIM + kk], acc);
  }
  const int off =
      ((((n >> 4) * 8 + (kk >> 5)) * 4 + ((kk >> 3) & 3)) * 16 + (n & 15)) * 8 +
      (kk & 7);
  Af[off] = (short)f2bf(acc);
}

// ---------------------------------------------------------------------------
// Kernel 3 (MFMA): per wave, 16 batch elements b = b0 + (lane&15).
// Y[n][b] = sum_k A[n][k] psi_b[k] via mfma_f32_16x16x32_bf16 with
//   A-operand: A-matrix fragments from LDS (staged 64-n-row chunks, 32 KB)
//   B-operand: psi fragments computed in registers (psi[k]=g[k>>4]*h[k&15])
// then z_b += sum_n psi[b][n] * Y[n][b] in-lane (C layout: col=b, row=n-local),
// reduced across q-groups with shfl_xor, sigmoid, store.
// ---------------------------------------------------------------------------
__global__ __launch_bounds__(256) void qcnn_mfma(const float* __restrict__ x,
                                                 const short* __restrict__ Af,
                                                 float* __restrict__ out) {
  __shared__ short sA[16384];  // one 32 KB chunk: 64 n-rows x 256 k (bf16)
  const int tid = threadIdx.x;
  const int lane = tid & 63;
  const int w = __builtin_amdgcn_readfirstlane(tid >> 6);
  const int c = lane & 15;
  const int q = lane >> 4;
  const int b = blockIdx.x * 64 + w * 16 + c;

  // --- per-lane batch element setup: cos/sin, g (wires 0-3), h (wires 4-7)
  const float4* xv = (const float4*)(x + (size_t)b * 8);
  const float4 x0 = xv[0];
  const float4 x1 = xv[1];
  const float xs[8] = {x0.x, x0.y, x0.z, x0.w, x1.x, x1.y, x1.z, x1.w};
  float cc[8], ss[8];
#pragma unroll
  for (int u = 0; u < 8; ++u) {
    cc[u] = __cosf(0.5f * xs[u]);
    ss[u] = __sinf(0.5f * xs[u]);
  }
  float g[16], h[16];
#pragma unroll
  for (int u = 0; u < 16; ++u) {
    g[u] = ((u & 8) ? ss[0] : cc[0]) * ((u & 4) ? ss[1] : cc[1]) *
           ((u & 2) ? ss[2] : cc[2]) * ((u & 1) ? ss[3] : cc[3]);
    h[u] = ((u & 8) ? ss[4] : cc[4]) * ((u & 4) ? ss[5] : cc[5]) *
           ((u & 2) ? ss[6] : cc[6]) * ((u & 1) ? ss[7] : cc[7]);
  }

  // --- B-operand (psi) fragments, one per 32-wide k-block.
  // Lane (q,c): frag element j = psi_b[32t + q*8 + j]
  //   = g[2t + (q>=2)] * h[(q&1)*8 + j]
  const int lo = q & 1;
  const int hi = (q >> 1) & 1;
  float hs[8];
#pragma unroll
  for (int j = 0; j < 8; ++j) hs[j] = lo ? h[8 + j] : h[j];
  float gk[8];
#pragma unroll
  for (int t = 0; t < 8; ++t) gk[t] = hi ? g[2 * t + 1] : g[2 * t];
  bf16x8 psi[8];
#pragma unroll
  for (int t = 0; t < 8; ++t) {
#pragma unroll
    for (int j = 0; j < 8; ++j) psi[t][j] = (short)f2bf(gk[t] * hs[j]);
  }
  // h values for the output dot: hd[r] = h[q*4 + r]
  float hd[4];
#pragma unroll
  for (int r = 0; r < 4; ++r) {
    hd[r] = (q & 2) ? ((q & 1) ? h[12 + r] : h[8 + r])
                    : ((q & 1) ? h[4 + r] : h[r]);
  }

  float z = 0.0f;
  const char* Abytes = (const char*)Af;
  char* sAbytes = (char*)sA;

#pragma unroll
  for (int nc = 0; nc < 4; ++nc) {
    if (nc) __syncthreads();  // previous chunk fully consumed
    // stage chunk nc: 32 KB contiguous, wave-cooperative global_load_lds x16B
#pragma unroll
    for (int i = 0; i < 8; ++i) {
      const char* gp = Abytes + (nc * 32768 + i * 4096 + w * 1024 + lane * 16);
      char* lp = sAbytes + (i * 4096 + w * 1024);  // wave-uniform dest
      __builtin_amdgcn_global_load_lds(
          (const __attribute__((address_space(1))) uint32_t*)gp,
          (__attribute__((address_space(3))) uint32_t*)lp, 16, 0, 0);
    }
    __syncthreads();

#pragma unroll
    for (int nt = 0; nt < 4; ++nt) {
      f32x4 acc = {0.0f, 0.0f, 0.0f, 0.0f};
#pragma unroll
      for (int t = 0; t < 8; ++t) {
        const bf16x8 a =
            *(const bf16x8*)(sA + (nt * 4096 + t * 512 + lane * 8));
        acc = __builtin_amdgcn_mfma_f32_16x16x32_bf16(a, psi[t], acc, 0, 0, 0);
      }
      // dot: rows n = (nc*4+nt)*16 + q*4 + r, so psi[b][n] = g[nc*4+nt]*hd[r]
      const float dot =
          hd[0] * acc[0] + hd[1] * acc[1] + hd[2] * acc[2] + hd[3] * acc[3];
      z = fmaf(g[nc * 4 + nt], dot, z);
    }
  }

  // reduce partial z across the 4 q-groups (same b lives in lanes c, c+16, ...)
  z += __shfl_xor(z, 16);
  z += __shfl_xor(z, 32);
  if (lane < 16) {
    out[blockIdx.x * 64 + w * 16 + lane] = 1.0f / (1.0f + __expf(-z));
  }
}

// ---------------------------------------------------------------------------
// ws layout: Ure[65536] f32 | Uim[65536] f32 | Af[65536] bf16  = 640 KB.
// ---------------------------------------------------------------------------
extern "C" void kernel_launch(void* const* d_in, const int* in_sizes, int n_in,
                              void* d_out, int out_size, void* d_ws, size_t ws_size,
                              hipStream_t stream) {
  const float* x = (const float*)d_in[0];
  const float* params = (const float*)d_in[1];
  float* out = (float*)d_out;
  float* Ure = (float*)d_ws;
  float* Uim = Ure + DIM * DIM;
  short* Af = (short*)(Uim + DIM * DIM);

  build_U<<<DIM, DIM, 0, stream>>>(params, Ure, Uim);
  build_A<<<DIM, DIM, 0, stream>>>(Ure, Uim, Af);

  const int B = in_sizes[0] / NQ;  // 131072
  qcnn_mfma<<<B / 64, 256, 0, stream>>>(x, Af, out);
}